// Round 3
// baseline (397.263 us; speedup 1.0000x reference)
//
#include <hip/hip_runtime.h>
#include <hip/hip_bf16.h>
#include <cstdint>

// ---------------------------------------------------------------------------
// MLPDecoder: logit[e] = relu([zu, zv, |zu-zv|] @ W1 + b1) @ W2 + b2
//   z: [100000,128] f32, edge_index: [2,E] int, W1: [384,128], b1:[128],
//   W2: [128,1], b2:[1].  Output: [E] f32.
//
// R3 (= R2 structure, register-budget-corrected):
//  - 256 persistent blocks x 512 threads (1 block/CU, 8 waves = 2/SIMD).
//  - Packed W1 (96KB) resident in LDS; B-frags via ds_read_b128.
//  - Wave = 32 edges x full 128 cols; no cross-wave reduce; the only
//    __syncthreads is after the one-time W1 staging.
//  - K-loop in c-groups (ks = c, 4+c, 8+c): after group c, zu/zv chunk c is
//    dead and the NEXT tile's chunk-c gather overwrites it IN PLACE.
//    Single AState (64 VGPR) instead of R2's ping-pong pair (128) and no
//    manual B dbuf: est ~200 VGPR, fits the 256 cap without spill.
// ---------------------------------------------------------------------------

typedef __bf16 bf16_t;
typedef __bf16 bf16x8 __attribute__((ext_vector_type(8)));
typedef float  floatx4 __attribute__((ext_vector_type(4)));

#define DIM 128
#define E_TILE 256          // edges per block-tile (8 waves x 32 edges)
#define N_KSTEP 12          // 384 / 32
#define N_NTILE 8           // 128 / 16
#define GRID_B 256          // persistent blocks (1 per CU)

// --- cast z fp32 -> bf16 ----------------------------------------------------
__global__ void cast_z_kernel(const float* __restrict__ z, bf16_t* __restrict__ zb, int n) {
    int idx = (blockIdx.x * 256 + threadIdx.x) * 8;
    if (idx + 8 > n) return;
    const float4* src = reinterpret_cast<const float4*>(z + idx);
    float4 a = src[0], b = src[1];
    bf16x8 o;
    o[0] = (bf16_t)a.x; o[1] = (bf16_t)a.y; o[2] = (bf16_t)a.z; o[3] = (bf16_t)a.w;
    o[4] = (bf16_t)b.x; o[5] = (bf16_t)b.y; o[6] = (bf16_t)b.z; o[7] = (bf16_t)b.w;
    *reinterpret_cast<bf16x8*>(zb + idx) = o;
}

// --- pack W1 [384,128] f32 row-major -> MFMA B-fragment order bf16 ----------
// frag index f = (kstep*8 + ntile); element j of lane l:
//   B[k = kstep*32 + (l>>4)*8 + j][n = ntile*16 + (l&15)]
// stored lane-contiguous: Wp[f*64 + lane] is a 16B bf16x8.
__global__ void pack_w1_kernel(const float* __restrict__ W1, bf16_t* __restrict__ Wp) {
    int f = blockIdx.x * 256 + threadIdx.x;     // 0 .. 12*8*64-1
    if (f >= N_KSTEP * N_NTILE * 64) return;
    int lane = f & 63;
    int nt   = (f >> 6) & 7;
    int ks   = f >> 9;
    int n  = nt * 16 + (lane & 15);
    int k0 = ks * 32 + (lane >> 4) * 8;
    bf16x8 o;
#pragma unroll
    for (int j = 0; j < 8; ++j) o[j] = (bf16_t)W1[(k0 + j) * DIM + n];
    reinterpret_cast<bf16x8*>(Wp)[f] = o;
}

// --- main fused kernel ------------------------------------------------------
template <bool PRECAST>
__global__ __launch_bounds__(512, 2)
void decode_kernel(const void* __restrict__ zsrc,
                   const int* __restrict__ ei,       // [2*E]
                   const bf16_t* __restrict__ Wp,    // packed W1 (96KB)
                   const float* __restrict__ b1,
                   const float* __restrict__ W2,
                   const float* __restrict__ b2,
                   float* __restrict__ out, int E) {
    __shared__ __align__(16) bf16_t Bsm[N_KSTEP * N_NTILE * 64 * 8];  // 96 KiB

    const int tid = threadIdx.x;

    // ---- stage packed W1 into LDS, once per persistent block ----
    {
        const uint4* src = reinterpret_cast<const uint4*>(Wp);
        uint4* dst = reinterpret_cast<uint4*>(Bsm);
#pragma unroll
        for (int i = 0; i < 12; ++i)            // 12 * 512 * 16B = 96 KiB
            dst[i * 512 + tid] = src[i * 512 + tid];
    }
    __syncthreads();    // the only block-wide barrier in the kernel

    const int wave = tid >> 6, lane = tid & 63;
    const int l15 = lane & 15, quad = lane >> 4;

    // ---- epilogue params (full n range per wave) ----
    float b1v[8], w2v[8];
#pragma unroll
    for (int nt = 0; nt < 8; ++nt) {
        int n = nt * 16 + l15;
        b1v[nt] = b1[n];
        w2v[nt] = W2[n];
    }
    const float bias2 = b2[0];

    const int ntiles = (E + E_TILE - 1) / E_TILE;

    // gather one 16B chunk of zu/zv for (mt, c): cols [c*32+quad*8, +8)
    auto gatherChunk = [&](bf16x8& du, bf16x8& dv, int nu, int nv, int c) {
        if (PRECAST) {
            const bf16_t* zb = (const bf16_t*)zsrc;
            du = *reinterpret_cast<const bf16x8*>(zb + (size_t)nu * DIM + c * 32 + quad * 8);
            dv = *reinterpret_cast<const bf16x8*>(zb + (size_t)nv * DIM + c * 32 + quad * 8);
        } else {
            const float* zf = (const float*)zsrc;
            const float4* pu = reinterpret_cast<const float4*>(zf + (size_t)nu * DIM + c * 32 + quad * 8);
            const float4* pv = reinterpret_cast<const float4*>(zf + (size_t)nv * DIM + c * 32 + quad * 8);
            float4 a = pu[0], b = pu[1];
            bf16x8 o;
            o[0] = (bf16_t)a.x; o[1] = (bf16_t)a.y; o[2] = (bf16_t)a.z; o[3] = (bf16_t)a.w;
            o[4] = (bf16_t)b.x; o[5] = (bf16_t)b.y; o[6] = (bf16_t)b.z; o[7] = (bf16_t)b.w;
            du = o;
            a = pv[0]; b = pv[1];
            o[0] = (bf16_t)a.x; o[1] = (bf16_t)a.y; o[2] = (bf16_t)a.z; o[3] = (bf16_t)a.w;
            o[4] = (bf16_t)b.x; o[5] = (bf16_t)b.y; o[6] = (bf16_t)b.z; o[7] = (bf16_t)b.w;
            dv = o;
        }
    };

    auto loadIdx = [&](int t, int mt, int& nu, int& nv) {
        int e = t * E_TILE + wave * 32 + mt * 16 + l15;
        if (e >= E) e = E - 1;                   // clamp: harmless duplicate work
        nu = ei[e];
        nv = ei[E + e];
    };

    auto loadB = [&](bf16x8* dst, int ks) {
#pragma unroll
        for (int nt = 0; nt < 8; ++nt)
            dst[nt] = *reinterpret_cast<const bf16x8*>(
                &Bsm[(size_t)((ks * N_NTILE + nt) * 64 + lane) * 8]);
    };

    // ---- single A state; prologue: fully gather tile blockIdx.x ----
    bf16x8 uz[2][4], vz[2][4];
    {
        int nu[2], nv[2];
#pragma unroll
        for (int mt = 0; mt < 2; ++mt) loadIdx(blockIdx.x, mt, nu[mt], nv[mt]);
#pragma unroll
        for (int mt = 0; mt < 2; ++mt)
#pragma unroll
            for (int c = 0; c < 4; ++c)
                gatherChunk(uz[mt][c], vz[mt][c], nu[mt], nv[mt], c);
    }

    // ---- persistent grid-stride loop ----
    for (int t = blockIdx.x; t < ntiles; t += GRID_B) {
        // next tile's node indices (prefetch target); clamped if past the end
        int nnu[2], nnv[2];
#pragma unroll
        for (int mt = 0; mt < 2; ++mt) loadIdx(t + GRID_B, mt, nnu[mt], nnv[mt]);

        floatx4 acc[2][8];
#pragma unroll
        for (int mt = 0; mt < 2; ++mt)
#pragma unroll
            for (int nt = 0; nt < 8; ++nt) acc[mt][nt] = (floatx4)0.0f;

        // K-loop: 4 c-groups of (ks=c, 4+c, 8+c). After group c, chunk c of
        // uz/vz is dead -> overwrite in place with next tile's gather.
#pragma unroll
        for (int c = 0; c < 4; ++c) {
            {   // ks = c : A = zu chunk c
                bf16x8 bc[8];
                loadB(bc, c);
#pragma unroll
                for (int mt = 0; mt < 2; ++mt)
#pragma unroll
                    for (int nt = 0; nt < 8; ++nt)
                        acc[mt][nt] = __builtin_amdgcn_mfma_f32_16x16x32_bf16(
                            uz[mt][c], bc[nt], acc[mt][nt], 0, 0, 0);
            }
            {   // ks = 4+c : A = zv chunk c
                bf16x8 bc[8];
                loadB(bc, 4 + c);
#pragma unroll
                for (int mt = 0; mt < 2; ++mt)
#pragma unroll
                    for (int nt = 0; nt < 8; ++nt)
                        acc[mt][nt] = __builtin_amdgcn_mfma_f32_16x16x32_bf16(
                            vz[mt][c], bc[nt], acc[mt][nt], 0, 0, 0);
            }
            {   // ks = 8+c : A = |zu - zv| chunk c
                bf16x8 bc[8];
                loadB(bc, 8 + c);
#pragma unroll
                for (int mt = 0; mt < 2; ++mt) {
                    bf16x8 u = uz[mt][c], v = vz[mt][c];
                    bf16x8 d;
#pragma unroll
                    for (int j = 0; j < 8; ++j)
                        d[j] = (bf16_t)fabsf((float)u[j] - (float)v[j]);
#pragma unroll
                    for (int nt = 0; nt < 8; ++nt)
                        acc[mt][nt] = __builtin_amdgcn_mfma_f32_16x16x32_bf16(
                            d, bc[nt], acc[mt][nt], 0, 0, 0);
                }
            }
            // chunk c dead: gather next tile's chunk c into the same registers
#pragma unroll
            for (int mt = 0; mt < 2; ++mt)
                gatherChunk(uz[mt][c], vz[mt][c], nnu[mt], nnv[mt], c);
        }

        // ---- epilogue: bias + relu + dot(W2), in-wave butterfly over n ----
        // C/D layout: n = nt*16 + l15, m = quad*4 + r
#pragma unroll
        for (int mt = 0; mt < 2; ++mt)
#pragma unroll
            for (int r = 0; r < 4; ++r) {
                float s = 0.f;
#pragma unroll
                for (int nt = 0; nt < 8; ++nt) {
                    float h = acc[mt][nt][r] + b1v[nt];
                    h = fmaxf(h, 0.f);
                    s += h * w2v[nt];
                }
                s += __shfl_xor(s, 1);
                s += __shfl_xor(s, 2);
                s += __shfl_xor(s, 4);
                s += __shfl_xor(s, 8);
                if (l15 == 0) {
                    int e = t * E_TILE + wave * 32 + mt * 16 + quad * 4 + r;
                    if (e < E) out[e] = s + bias2;
                }
            }
    }
}

// ---------------------------------------------------------------------------
extern "C" void kernel_launch(void* const* d_in, const int* in_sizes, int n_in,
                              void* d_out, int out_size, void* d_ws, size_t ws_size,
                              hipStream_t stream) {
    const float* z  = (const float*)d_in[0];
    const int*   ei = (const int*)d_in[1];
    const float* W1 = (const float*)d_in[2];
    const float* b1 = (const float*)d_in[3];
    const float* W2 = (const float*)d_in[4];
    const float* b2 = (const float*)d_in[5];
    float* out = (float*)d_out;

    const int E  = in_sizes[1] / 2;
    const int zn = in_sizes[0];

    const size_t zb_bytes = (size_t)zn * sizeof(bf16_t);
    const size_t wp_bytes = (size_t)N_KSTEP * N_NTILE * 64 * 16;  // 98304
    const bool precast = ws_size >= zb_bytes + wp_bytes;

    bf16_t* zb = (bf16_t*)d_ws;
    bf16_t* wp = precast ? (bf16_t*)((char*)d_ws + zb_bytes) : (bf16_t*)d_ws;

    hipLaunchKernelGGL(pack_w1_kernel, dim3((N_KSTEP * N_NTILE * 64 + 255) / 256),
                       dim3(256), 0, stream, W1, wp);

    if (precast) {
        hipLaunchKernelGGL(cast_z_kernel, dim3((zn / 8 + 255) / 256), dim3(256),
                           0, stream, z, zb, zn);
        hipLaunchKernelGGL((decode_kernel<true>), dim3(GRID_B), dim3(512), 0,
                           stream, (const void*)zb, ei, wp, b1, W2, b2, out, E);
    } else {
        hipLaunchKernelGGL((decode_kernel<false>), dim3(GRID_B), dim3(512), 0,
                           stream, (const void*)z, ei, wp, b1, W2, b2, out, E);
    }
}